// Round 2
// baseline (64.864 us; speedup 1.0000x reference)
//
#include <hip/hip_runtime.h>
#include <math.h>

#define B_SZ   2048
#define D_SZ   4096
#define NBASIS 8
#define TB     16            // batch rows per block
#define NC     16            // d-chunks
#define DC     256           // d's per chunk (== blockDim)
#define NBG    (B_SZ / TB)   // 128 batch groups

// ws layout: cnt[NBG] ints (padded to 1KB) + partial[NBG][NC][TB][3] floats
#define WS_CNT_BYTES   1024
#define WS_PART_BYTES  (NBG * NC * TB * 3 * 4)

// ---------------------------------------------------------------------------
// Single fused kernel: per-block coef staging, spline+silu accumulate,
// shuffle-based block reduction, split-K style last-block final reduce.
__global__ __launch_bounds__(256) void kan_fused(
    const float* __restrict__ x, const float* __restrict__ grid,
    const float* __restrict__ coef, const float* __restrict__ sb,
    const float* __restrict__ ssp,  const float* __restrict__ mask,
    float* __restrict__ partial, int* __restrict__ cnt, float* __restrict__ out)
{
    __shared__ float4 effc[NBASIS * DC];   // 32 KB; reused as reduction scratch
    __shared__ int s_last;

    const int tid = threadIdx.x;
    const int bg  = blockIdx.x;            // 0 .. NBG-1
    const int dc  = blockIdx.y;            // 0 .. NC-1
    const int d   = dc * DC + tid;

    // ---- fused precompute: effc[n][tid] = coef[d][o][n] * ssp[d][o] * mask ----
    float m0 = mask[d*3+0], m1 = mask[d*3+1], m2 = mask[d*3+2];
    float s0 = ssp[d*3+0]*m0, s1 = ssp[d*3+1]*m1, s2 = ssp[d*3+2]*m2;
    float eb0 = sb[d*3+0]*m0, eb1 = sb[d*3+1]*m1, eb2 = sb[d*3+2]*m2;
    {
        const float4* cv = (const float4*)(coef + (size_t)d * 24);
        float4 ca = cv[0], cb = cv[1], cc = cv[2], cd = cv[3], ce = cv[4], cf = cv[5];
        float p0[8] = {ca.x,ca.y,ca.z,ca.w, cb.x,cb.y,cb.z,cb.w};
        float p1[8] = {cc.x,cc.y,cc.z,cc.w, cd.x,cd.y,cd.z,cd.w};
        float p2[8] = {ce.x,ce.y,ce.z,ce.w, cf.x,cf.y,cf.z,cf.w};
        #pragma unroll
        for (int n = 0; n < NBASIS; ++n)
            effc[n*DC + tid] = make_float4(p0[n]*s0, p1[n]*s1, p2[n]*s2, 0.0f);
    }

    const float g3   = grid[3];                     // -1
    const float invh = 1.0f / (grid[4] - grid[3]);  // 2.5
    __syncthreads();

    // ---- main loop: 16 batch rows, one d per thread ----
    const int b0 = bg * TB;
    const float* xp = x + (size_t)b0 * D_SZ + d;
    float xv[TB];
    #pragma unroll
    for (int q = 0; q < TB; ++q) xv[q] = xp[(size_t)q * D_SZ];

    float acc[TB][3];
    #pragma unroll
    for (int q = 0; q < TB; ++q) {
        float X = xv[q];
        float u   = (X - g3) * invh;
        float cfl = floorf(u);
        cfl = fminf(fmaxf(cfl, 0.0f), 4.0f);
        int   cell = (int)cfl;
        float t  = u - cfl;
        float t2 = t*t, t3 = t2*t;
        float omt = 1.0f - t;
        float w0 = omt*omt*omt*(1.0f/6.0f);
        float w1 = (3.0f*t3 - 6.0f*t2 + 4.0f)*(1.0f/6.0f);
        float w2 = (-3.0f*t3 + 3.0f*t2 + 3.0f*t + 1.0f)*(1.0f/6.0f);
        float w3 = t3*(1.0f/6.0f);
        float sil = X / (1.0f + __expf(-X));

        const float4* cp = &effc[cell * DC + tid];
        float4 k0 = cp[0];
        float4 k1 = cp[DC];
        float4 k2 = cp[2*DC];
        float4 k3 = cp[3*DC];
        acc[q][0] = w0*k0.x + w1*k1.x + w2*k2.x + w3*k3.x + sil*eb0;
        acc[q][1] = w0*k0.y + w1*k1.y + w2*k2.y + w3*k3.y + sil*eb1;
        acc[q][2] = w0*k0.z + w1*k1.z + w2*k2.z + w3*k3.z + sil*eb2;
    }

    // ---- block reduction: LDS transpose + wave shuffle butterfly ----
    float* red = (float*)effc;             // 8192 floats; use 24*256 = 6144
    const int lane = tid & 63;
    const int wv   = tid >> 6;
    #pragma unroll
    for (int half = 0; half < 2; ++half) {
        __syncthreads();                   // WAR on previous LDS use
        #pragma unroll
        for (int q = 0; q < 8; ++q)
            #pragma unroll
            for (int o = 0; o < 3; ++o)
                red[(q*3 + o)*DC + tid] = acc[half*8 + q][o];
        __syncthreads();
        #pragma unroll
        for (int j = 0; j < 6; ++j) {
            int r = wv*6 + j;              // 24 rows / 4 waves
            float4 v = *(const float4*)&red[r*DC + lane*4];
            float s = (v.x + v.y) + (v.z + v.w);
            #pragma unroll
            for (int off = 1; off < 64; off <<= 1)
                s += __shfl_xor(s, off, 64);
            if (lane == 0) {
                int q = half*8 + r/3, o = r % 3;
                __hip_atomic_store(&partial[((size_t)(bg*NC + dc)*TB + q)*3 + o], s,
                                   __ATOMIC_RELAXED, __HIP_MEMORY_SCOPE_AGENT);
            }
        }
    }

    // ---- split-K fixup: last dc-block for this bg does the final reduce ----
    __syncthreads();                       // all waves' partial stores retired
    if (tid == 0) {
        int old = __hip_atomic_fetch_add(&cnt[bg], 1, __ATOMIC_ACQ_REL,
                                         __HIP_MEMORY_SCOPE_AGENT);
        s_last = (old == NC - 1) ? 1 : 0;
    }
    __syncthreads();
    if (s_last && tid < TB*3) {
        int q = tid / 3, o = tid % 3;
        float s = 0.0f;
        #pragma unroll
        for (int c = 0; c < NC; ++c)
            s += __hip_atomic_load(&partial[((size_t)(bg*NC + c)*TB + q)*3 + o],
                                   __ATOMIC_RELAXED, __HIP_MEMORY_SCOPE_AGENT);
        out[(size_t)(bg*TB + q)*3 + o] = s;
    }
}

// ---------------------------------------------------------------------------
// Fallback (no workspace): block per b, raw arrays. Slower but correct.
__global__ __launch_bounds__(256) void kan_fallback(
    const float* __restrict__ x, const float* __restrict__ grid,
    const float* __restrict__ coef, const float* __restrict__ sb,
    const float* __restrict__ ssp,  const float* __restrict__ mask,
    float* __restrict__ out)
{
    __shared__ float red[3][4];
    int b = blockIdx.x, tid = threadIdx.x;
    float g3 = grid[3], invh = 1.0f / (grid[4] - grid[3]);
    float acc[3] = {0.f, 0.f, 0.f};
    for (int i = 0; i < D_SZ / 256; ++i) {
        int d = i * 256 + tid;
        float xv = x[(size_t)b * D_SZ + d];
        float u  = (xv - g3) * invh;
        float cfl = floorf(u);
        cfl = fminf(fmaxf(cfl, 0.0f), 4.0f);
        int  cell = (int)cfl;
        float t  = u - cfl;
        float t2 = t * t, t3 = t2 * t;
        float omt = 1.0f - t;
        float w0 = omt*omt*omt * (1.0f/6.0f);
        float w1 = (3.0f*t3 - 6.0f*t2 + 4.0f) * (1.0f/6.0f);
        float w2 = (-3.0f*t3 + 3.0f*t2 + 3.0f*t + 1.0f) * (1.0f/6.0f);
        float w3 = t3 * (1.0f/6.0f);
        float sil = xv / (1.0f + __expf(-xv));
        #pragma unroll
        for (int o = 0; o < 3; ++o) {
            const float* cp = &coef[(d*3 + o) * NBASIS + cell];
            float s = w0*cp[0] + w1*cp[1] + w2*cp[2] + w3*cp[3];
            float m = mask[d*3 + o];
            acc[o] += s * ssp[d*3 + o] * m + sil * sb[d*3 + o] * m;
        }
    }
    int lane = tid & 63, wv = tid >> 6;
    #pragma unroll
    for (int o = 0; o < 3; ++o) {
        float v = acc[o];
        #pragma unroll
        for (int off = 32; off >= 1; off >>= 1) v += __shfl_down(v, off, 64);
        if (lane == 0) red[o][wv] = v;
    }
    __syncthreads();
    if (tid < 3) {
        float s = red[tid][0] + red[tid][1] + red[tid][2] + red[tid][3];
        out[b * 3 + tid] = s;
    }
}

// ---------------------------------------------------------------------------
extern "C" void kernel_launch(void* const* d_in, const int* in_sizes, int n_in,
                              void* d_out, int out_size, void* d_ws, size_t ws_size,
                              hipStream_t stream)
{
    const float* x    = (const float*)d_in[0];
    const float* grid = (const float*)d_in[4];
    const float* coef = (const float*)d_in[5];
    const float* sb   = (const float*)d_in[6];
    const float* ssp  = (const float*)d_in[7];
    const float* mask = (const float*)d_in[8];
    float* out = (float*)d_out;

    size_t need = (size_t)WS_CNT_BYTES + WS_PART_BYTES;
    if (ws_size >= need) {
        int*   cnt     = (int*)d_ws;
        float* partial = (float*)((char*)d_ws + WS_CNT_BYTES);
        hipMemsetAsync(cnt, 0, NBG * sizeof(int), stream);
        dim3 g(NBG, NC);
        kan_fused<<<g, 256, 0, stream>>>(x, grid, coef, sb, ssp, mask,
                                         partial, cnt, out);
    } else {
        kan_fallback<<<B_SZ, 256, 0, stream>>>(x, grid, coef, sb, ssp, mask, out);
    }
}

// Round 3
// 57.491 us; speedup vs baseline: 1.1283x; 1.1283x over previous
//
#include <hip/hip_runtime.h>
#include <math.h>

#define B_SZ   2048
#define D_SZ   4096
#define NBASIS 8
#define TB     16            // batch rows per block
#define NC     16            // d-chunks
#define DC     256           // d's per chunk (== blockDim)
#define NBG    (B_SZ / TB)   // 128 batch groups

// ws layout: partial[NC][B_SZ][3] floats
#define WS_PART_BYTES  (NC * B_SZ * 3 * 4)

// ---------------------------------------------------------------------------
// Fused main kernel: per-block coef precompute, spline+silu accumulate,
// conflict-free shuffle reduction, plain partial stores (no atomics).
__global__ __launch_bounds__(256, 4) void kan_main(
    const float* __restrict__ x, const float* __restrict__ grid,
    const float* __restrict__ coef, const float* __restrict__ sb,
    const float* __restrict__ ssp,  const float* __restrict__ mask,
    float* __restrict__ partial)
{
    __shared__ float4 effc[NBASIS * DC];   // 32 KB; reused as reduction scratch

    const int tid = threadIdx.x;
    const int bg  = blockIdx.x;            // 0 .. NBG-1
    const int dc  = blockIdx.y;            // 0 .. NC-1
    const int d   = dc * DC + tid;

    // ---- fused precompute: effc[n][tid] = coef[d][o][n] * ssp[d][o] * mask ----
    float m0 = mask[d*3+0], m1 = mask[d*3+1], m2 = mask[d*3+2];
    float s0 = ssp[d*3+0]*m0, s1 = ssp[d*3+1]*m1, s2 = ssp[d*3+2]*m2;
    float eb0 = sb[d*3+0]*m0, eb1 = sb[d*3+1]*m1, eb2 = sb[d*3+2]*m2;
    {
        const float4* cv = (const float4*)(coef + (size_t)d * 24);
        float4 ca = cv[0], cb = cv[1], cc = cv[2], cd = cv[3], ce = cv[4], cf4 = cv[5];
        float p0[8] = {ca.x,ca.y,ca.z,ca.w, cb.x,cb.y,cb.z,cb.w};
        float p1[8] = {cc.x,cc.y,cc.z,cc.w, cd.x,cd.y,cd.z,cd.w};
        float p2[8] = {ce.x,ce.y,ce.z,ce.w, cf4.x,cf4.y,cf4.z,cf4.w};
        #pragma unroll
        for (int n = 0; n < NBASIS; ++n)
            effc[n*DC + tid] = make_float4(p0[n]*s0, p1[n]*s1, p2[n]*s2, 0.0f);
    }

    const float g3   = grid[3];                     // -1
    const float invh = 1.0f / (grid[4] - grid[3]);  // 2.5
    __syncthreads();

    // ---- main loop: 16 batch rows, one d per thread ----
    const int b0 = bg * TB;
    const float* xp = x + (size_t)b0 * D_SZ + d;
    float xv[TB];
    #pragma unroll
    for (int q = 0; q < TB; ++q) xv[q] = xp[(size_t)q * D_SZ];

    float acc[TB][3];
    #pragma unroll
    for (int q = 0; q < TB; ++q) {
        float X = xv[q];
        // uniform cubic B-spline, lean closed form
        float u   = fmaf(X, invh, -g3 * invh);     // (X - g3)/h
        float cfl = fminf(fmaxf(truncf(u), 0.0f), 4.0f);
        int   cell = (int)cfl;
        float t  = u - cfl;
        float t2 = t*t, t3 = t2*t;
        float w0 = fmaf(fmaf(fmaf(t, -1.0f/6.0f, 0.5f), t, -0.5f), t, 1.0f/6.0f);
        float w1 = fmaf(fmaf(t, 0.5f, -1.0f), t2, 2.0f/3.0f);
        float w3 = t3 * (1.0f/6.0f);
        float w2 = 1.0f - w0 - w1 - w3;
        float e   = __expf(-X);
        float sil = X * __builtin_amdgcn_rcpf(1.0f + e);

        const float4* cp = &effc[cell * DC + tid];
        float4 k0 = cp[0];
        float4 k1 = cp[DC];
        float4 k2 = cp[2*DC];
        float4 k3 = cp[3*DC];
        acc[q][0] = fmaf(w0,k0.x, fmaf(w1,k1.x, fmaf(w2,k2.x, fmaf(w3,k3.x, sil*eb0))));
        acc[q][1] = fmaf(w0,k0.y, fmaf(w1,k1.y, fmaf(w2,k2.y, fmaf(w3,k3.y, sil*eb1))));
        acc[q][2] = fmaf(w0,k0.z, fmaf(w1,k1.z, fmaf(w2,k2.z, fmaf(w3,k3.z, sil*eb2))));
    }

    // ---- block reduction: LDS transpose + wave shuffle butterfly ----
    float* red = (float*)effc;             // 8192 floats; use 24*256 = 6144
    const int lane = tid & 63;
    const int wv   = tid >> 6;
    #pragma unroll
    for (int half = 0; half < 2; ++half) {
        __syncthreads();                   // WAR on previous LDS use
        #pragma unroll
        for (int q = 0; q < 8; ++q)
            #pragma unroll
            for (int o = 0; o < 3; ++o)
                red[(q*3 + o)*DC + tid] = acc[half*8 + q][o];
        __syncthreads();
        #pragma unroll
        for (int j = 0; j < 6; ++j) {
            int r = wv*6 + j;              // 24 rows / 4 waves
            float4 v = *(const float4*)&red[r*DC + lane*4];
            float s = (v.x + v.y) + (v.z + v.w);
            #pragma unroll
            for (int off = 1; off < 64; off <<= 1)
                s += __shfl_xor(s, off, 64);
            if (lane == 0) {
                int q = half*8 + r/3, o = r % 3;
                partial[((size_t)dc * B_SZ + (b0 + q))*3 + o] = s;
            }
        }
    }
}

// ---------------------------------------------------------------------------
__global__ __launch_bounds__(256) void reduce_partials(
    const float* __restrict__ partial, float* __restrict__ out)
{
    int i = blockIdx.x * 256 + threadIdx.x;
    if (i >= B_SZ * 3) return;
    float s = 0.0f;
    #pragma unroll
    for (int c = 0; c < NC; ++c) s += partial[(size_t)c * B_SZ * 3 + i];
    out[i] = s;
}

// ---------------------------------------------------------------------------
// Fallback (no workspace): block per b, raw arrays. Slower but correct.
__global__ __launch_bounds__(256) void kan_fallback(
    const float* __restrict__ x, const float* __restrict__ grid,
    const float* __restrict__ coef, const float* __restrict__ sb,
    const float* __restrict__ ssp,  const float* __restrict__ mask,
    float* __restrict__ out)
{
    __shared__ float red[3][4];
    int b = blockIdx.x, tid = threadIdx.x;
    float g3 = grid[3], invh = 1.0f / (grid[4] - grid[3]);
    float acc[3] = {0.f, 0.f, 0.f};
    for (int i = 0; i < D_SZ / 256; ++i) {
        int d = i * 256 + tid;
        float xv = x[(size_t)b * D_SZ + d];
        float u  = (xv - g3) * invh;
        float cfl = floorf(u);
        cfl = fminf(fmaxf(cfl, 0.0f), 4.0f);
        int  cell = (int)cfl;
        float t  = u - cfl;
        float t2 = t * t, t3 = t2 * t;
        float omt = 1.0f - t;
        float w0 = omt*omt*omt * (1.0f/6.0f);
        float w1 = (3.0f*t3 - 6.0f*t2 + 4.0f) * (1.0f/6.0f);
        float w2 = (-3.0f*t3 + 3.0f*t2 + 3.0f*t + 1.0f) * (1.0f/6.0f);
        float w3 = t3 * (1.0f/6.0f);
        float sil = xv / (1.0f + __expf(-xv));
        #pragma unroll
        for (int o = 0; o < 3; ++o) {
            const float* cp = &coef[(d*3 + o) * NBASIS + cell];
            float s = w0*cp[0] + w1*cp[1] + w2*cp[2] + w3*cp[3];
            float m = mask[d*3 + o];
            acc[o] += s * ssp[d*3 + o] * m + sil * sb[d*3 + o] * m;
        }
    }
    int lane = tid & 63, wv = tid >> 6;
    #pragma unroll
    for (int o = 0; o < 3; ++o) {
        float v = acc[o];
        #pragma unroll
        for (int off = 32; off >= 1; off >>= 1) v += __shfl_down(v, off, 64);
        if (lane == 0) red[o][wv] = v;
    }
    __syncthreads();
    if (tid < 3) {
        float s = red[tid][0] + red[tid][1] + red[tid][2] + red[tid][3];
        out[b * 3 + tid] = s;
    }
}

// ---------------------------------------------------------------------------
extern "C" void kernel_launch(void* const* d_in, const int* in_sizes, int n_in,
                              void* d_out, int out_size, void* d_ws, size_t ws_size,
                              hipStream_t stream)
{
    const float* x    = (const float*)d_in[0];
    const float* grid = (const float*)d_in[4];
    const float* coef = (const float*)d_in[5];
    const float* sb   = (const float*)d_in[6];
    const float* ssp  = (const float*)d_in[7];
    const float* mask = (const float*)d_in[8];
    float* out = (float*)d_out;

    if (ws_size >= (size_t)WS_PART_BYTES) {
        float* partial = (float*)d_ws;
        dim3 g(NBG, NC);
        kan_main<<<g, 256, 0, stream>>>(x, grid, coef, sb, ssp, mask, partial);
        reduce_partials<<<(B_SZ*3 + 255)/256, 256, 0, stream>>>(partial, out);
    } else {
        kan_fallback<<<B_SZ, 256, 0, stream>>>(x, grid, coef, sb, ssp, mask, out);
    }
}